// Round 25
// baseline (80.047 us; speedup 1.0000x reference)
//
#include <hip/hip_runtime.h>

// Nearest-prototype argmin: N=500k, K=256, D=64, fp32.
// R25 = R24 (best-equivalent: autonomous waves, protos as LDS fragments,
// register seeds, no in-loop barriers) with the THIRD DISPATCH DELETED:
// the hipMemsetAsync counter-reset is replaced by a per-wave SEGMENTED
// flag list -- wave gwid owns ws_seg[gwid][120] and writes ws_cnt[gwid]
// unconditionally every call (fully overwritten -> replay-safe, no reset,
// no atomics, no readback). Overflow (>120 flags/wave; avg is ~3) flags
// bit 31 in out and the fixup scans just that wave's <=128-pt range.
// Main-loop numerics byte-identical to R22/R24 (absmax=0 heritage).

#define DIM 64
#define NPROTO 256
#define NBLK 1024
#define NWAVE (NBLK * 4)          // 4096 autonomous waves
#define SEGC 120                  // per-wave segment capacity
#define MARGIN_ACC 0.017f

using f32x4 = __attribute__((ext_vector_type(4))) float;
using f16x8 = __attribute__((ext_vector_type(8))) _Float16;

__device__ __forceinline__ f16x8 cvt8(float4 a, float4 b) {
    f16x8 r;
    r[0] = (_Float16)a.x; r[1] = (_Float16)a.y;
    r[2] = (_Float16)a.z; r[3] = (_Float16)a.w;
    r[4] = (_Float16)b.x; r[5] = (_Float16)b.y;
    r[6] = (_Float16)b.z; r[7] = (_Float16)b.w;
    return r;
}

__global__ void __launch_bounds__(256)
argmin_mfma_kernel(const float* __restrict__ X,
                   const float* __restrict__ mus,
                   int* __restrict__ out,
                   unsigned* __restrict__ ws_cnt,
                   int* __restrict__ ws_seg,
                   int use_list, int n) {
    // [p][kt][lane]: lane l's fragment for proto-tile p, K-half kt.
    __shared__ __align__(16) f16x8 s_frag[16][2][64];   // 32 KB
    __shared__ __align__(16) float s_seed[NPROTO];      // -0.5*musq

    const int tid = threadIdx.x;   // 256 = 4 waves
    const int w = tid >> 6;
    const int l = tid & 63;
    const int lp = l & 15;         // A-row / B-col lane index
    const int lg = l >> 4;         // k-group

    // ---- prologue: wave w stages proto-tiles p = w*4 .. w*4+3 ----
#pragma unroll
    for (int pp = 0; pp < 4; ++pp) {
        const int p = w * 4 + pp;
        const float* src = mus + (size_t)(p * 16 + lp) * DIM + lg * 8;
        const float4 a = *(const float4*)(src);
        const float4 b = *(const float4*)(src + 4);
        const float4 c = *(const float4*)(src + 32);
        const float4 d = *(const float4*)(src + 36);
        s_frag[p][0][l] = cvt8(a, b);
        s_frag[p][1][l] = cvt8(c, d);
        float s = 0.f;
        s = fmaf(a.x, a.x, fmaf(a.y, a.y, fmaf(a.z, a.z, fmaf(a.w, a.w, s))));
        s = fmaf(b.x, b.x, fmaf(b.y, b.y, fmaf(b.z, b.z, fmaf(b.w, b.w, s))));
        s = fmaf(c.x, c.x, fmaf(c.y, c.y, fmaf(c.z, c.z, fmaf(c.w, c.w, s))));
        s = fmaf(d.x, d.x, fmaf(d.y, d.y, fmaf(d.z, d.z, fmaf(d.w, d.w, s))));
        s += __shfl_xor(s, 16);
        s += __shfl_xor(s, 32);
        if (lg == 0) s_seed[p * 16 + lp] = -0.5f * s;
    }
    __syncthreads();   // the ONLY barrier: publish fragments + seed

    // seeds -> registers (iteration-invariant), 64 VGPR
    f32x4 mh[16];
#pragma unroll
    for (int p = 0; p < 16; ++p)
        mh[p] = *(const f32x4*)&s_seed[p * 16 + lg * 4];

    // ---- 16-point group range per GLOBAL wave (autonomous) ----
    const int ngroups = (n + 15) / 16;   // 31250
    const int gwid = blockIdx.x * 4 + w;
    const int q = ngroups / NWAVE, rr = ngroups % NWAVE;
    const int g0 = gwid * q + (gwid < rr ? gwid : rr);
    const int cnt = q + (gwid < rr ? 1 : 0);

    const int kofs = 255 - lg * 4;   // packed value = 255 - kk

    // prefetch group g0
    float4 xr0, xr1, xr2, xr3;
    if (cnt > 0) {
        int row = g0 * 16 + lp; row = (row < n) ? row : (n - 1);
        const float* rp = X + (size_t)row * DIM + lg * 8;
        xr0 = *(const float4*)(rp);
        xr1 = *(const float4*)(rp + 4);
        xr2 = *(const float4*)(rp + 32);
        xr3 = *(const float4*)(rp + 36);
    }

    unsigned fc = 0;   // per-wave flag count (uniform across lanes)

    for (int it = 0; it < cnt; ++it) {
        const int g = g0 + it;
        const bool more = (it + 1 < cnt);

        const f16x8 bx0 = cvt8(xr0, xr1);
        const f16x8 bx1 = cvt8(xr2, xr3);

        if (more) {
            int row = (g + 1) * 16 + lp; row = (row < n) ? row : (n - 1);
            const float* rp = X + (size_t)row * DIM + lg * 8;
            xr0 = *(const float4*)(rp);
            xr1 = *(const float4*)(rp + 4);
            xr2 = *(const float4*)(rp + 32);
            xr3 = *(const float4*)(rp + 36);
        }

        float b1 = -3.4e38f, b2 = -3.4e38f;
#pragma unroll
        for (int p = 0; p < 16; ++p) {
            const f16x8 A0 = s_frag[p][0][l];
            const f16x8 A1 = s_frag[p][1][l];
            f32x4 acc = __builtin_amdgcn_mfma_f32_16x16x32_f16(
                A0, bx0, mh[p], 0, 0, 0);
            acc = __builtin_amdgcn_mfma_f32_16x16x32_f16(A1, bx1, acc,
                                                         0, 0, 0);
            float pv[4];
#pragma unroll
            for (int r = 0; r < 4; ++r) {
                unsigned u = __float_as_uint(acc[r]);
                u = (u & 0xFFFFFF00u) + (unsigned)(kofs - p * 16 - r);
                pv[r] = __uint_as_float(u);
            }
            const float t1a = fmaxf(pv[0], pv[1]), t2a = fminf(pv[0], pv[1]);
            const float t1b = fmaxf(pv[2], pv[3]), t2b = fminf(pv[2], pv[3]);
            const float p1 = fmaxf(t1a, t1b);
            const float p2 = fmaxf(fminf(t1a, t1b), fmaxf(t2a, t2b));
            const float nb2 = fmaxf(fminf(b1, p1), fmaxf(b2, p2));
            b1 = fmaxf(b1, p1);
            b2 = nb2;
        }
#pragma unroll
        for (int m = 16; m <= 32; m <<= 1) {
            const float o1 = __shfl_xor(b1, m);
            const float o2 = __shfl_xor(b2, m);
            const float nb2 = fmaxf(fminf(b1, o1), fmaxf(b2, o2));
            b1 = fmaxf(b1, o1);
            b2 = nb2;
        }

        const int i = g * 16 + l;   // valid for l < 16
        const bool mine = (l < 16 && i < n);
        int k1 = 0;
        bool close = false;
        if (mine) {
            const unsigned u1 = __float_as_uint(b1);
            k1 = 255 - (int)(u1 & 0xFFu);
            const float v1 = __uint_as_float(u1 & 0xFFFFFF00u);
            const float v2 =
                __uint_as_float(__float_as_uint(b2) & 0xFFFFFF00u);
            close = (v1 - v2) < MARGIN_ACC;
        }
        if (use_list) {
            const bool fl = mine && close;
            const unsigned long long mask = __ballot(fl);
            const unsigned off = (unsigned)__popcll(mask & ((1ull << l) - 1));
            if (mine) {
                const unsigned idx = fc + off;
                if (!close) {
                    out[i] = k1;
                } else if (idx < SEGC) {
                    out[i] = k1;                       // clean; goes to list
                    ws_seg[gwid * SEGC + (int)idx] = i;
                } else {
                    out[i] = (int)((unsigned)k1 | 0x80000000u);  // overflow
                }
            }
            fc += (unsigned)__popcll(mask);
        } else if (mine) {
            out[i] = (int)((unsigned)k1 | (close ? 0x80000000u : 0u));
        }
    }
    if (use_list && l == 0) ws_cnt[gwid] = fc;  // written EVERY call
}

#define MSTRIDE 65   // padded row stride: bank (l+d)%32, 2 lanes/bank = free

// wave-cooperative exact-fp32 recompute of one point from LDS-staged mus
__device__ __forceinline__ void fix_point(const float* __restrict__ X,
                                          const float* s_mu,
                                          const float* s_msq,
                                          int* __restrict__ out,
                                          int pt, int l) {
    const float4* xr = (const float4*)(X + (size_t)pt * DIM);
    float4 xv[16];
    float a0 = 0.f, a1 = 0.f, a2 = 0.f, a3 = 0.f;
#pragma unroll
    for (int qq = 0; qq < 16; ++qq) {
        xv[qq] = xr[qq];
        a0 = fmaf(xv[qq].x, xv[qq].x, a0);
        a1 = fmaf(xv[qq].y, xv[qq].y, a1);
        a2 = fmaf(xv[qq].z, xv[qq].z, a2);
        a3 = fmaf(xv[qq].w, xv[qq].w, a3);
    }
    const float xsq = (a0 + a1) + (a2 + a3);
    float b1 = 3.4e38f;
    int k1 = 0;
#pragma unroll
    for (int e = 0; e < 4; ++e) {
        const int p = e * 64 + l;           // k ascending per lane
        const float* mr = &s_mu[p * MSTRIDE];
        float d0 = 0.f, d1 = 0.f, d2 = 0.f, d3 = 0.f;
#pragma unroll
        for (int qq = 0; qq < 16; ++qq) {
            d0 = fmaf(mr[qq * 4],     xv[qq].x, d0);
            d1 = fmaf(mr[qq * 4 + 1], xv[qq].y, d1);
            d2 = fmaf(mr[qq * 4 + 2], xv[qq].z, d2);
            d3 = fmaf(mr[qq * 4 + 3], xv[qq].w, d3);
        }
        const float dot = (d0 + d1) + (d2 + d3);
        const float dd = (xsq - 2.0f * dot) + s_msq[p];
        if (dd < b1) { b1 = dd; k1 = p; }   // strict <: first-min
    }
#pragma unroll
    for (int mm = 1; mm < 64; mm <<= 1) {
        const float ob = __shfl_xor(b1, mm);
        const int ok = __shfl_xor(k1, mm);
        if (ob < b1 || (ob == b1 && ok < k1)) { b1 = ob; k1 = ok; }
    }
    if (l == 0) out[pt] = k1;
}

// Segment-driven fixup: stage mus (+msq, R2 4-stripe order) in LDS once per
// block; grid-stride over the 4096 wave segments; overflowed segments also
// scan their wave's <=128-point range for bit-31 flags.
__global__ void __launch_bounds__(256)
fixup_seg_kernel(const float* __restrict__ X, const float* __restrict__ mus,
                 const unsigned* __restrict__ ws_cnt,
                 const int* __restrict__ ws_seg,
                 int* __restrict__ out, int n) {
    __shared__ float s_mu[NPROTO * MSTRIDE];  // 65 KB
    __shared__ float s_msq[NPROTO];

    const int tid = threadIdx.x;
    {
        const float4* mr = (const float4*)(mus + (size_t)tid * DIM);
        float q0 = 0.f, q1 = 0.f, q2 = 0.f, q3 = 0.f;
#pragma unroll
        for (int qq = 0; qq < 16; ++qq) {
            const float4 mv = mr[qq];
            const int base = tid * MSTRIDE + qq * 4;
            s_mu[base]     = mv.x;
            s_mu[base + 1] = mv.y;
            s_mu[base + 2] = mv.z;
            s_mu[base + 3] = mv.w;
            q0 = fmaf(mv.x, mv.x, q0);
            q1 = fmaf(mv.y, mv.y, q1);
            q2 = fmaf(mv.z, mv.z, q2);
            q3 = fmaf(mv.w, mv.w, q3);
        }
        s_msq[tid] = (q0 + q1) + (q2 + q3);
    }
    __syncthreads();

    const int l = tid & 63;
    const int fw = (int)((blockIdx.x * blockDim.x + tid) >> 6);
    const int NWf = (int)((gridDim.x * blockDim.x) >> 6);

    const int ngroups = (n + 15) / 16;
    const int q = ngroups / NWAVE, rr = ngroups % NWAVE;

    for (int wid = fw; wid < NWAVE; wid += NWf) {
        const unsigned c = ws_cnt[wid];
        const unsigned m = (c < SEGC) ? c : SEGC;
        for (unsigned j = 0; j < m; ++j) {
            const int pt = ws_seg[wid * SEGC + (int)j];
            fix_point(X, s_mu, s_msq, out, pt, l);
        }
        if (c > SEGC) {
            // overflow: scan this wave's point range for bit-31 flags
            const int g0 = wid * q + (wid < rr ? wid : rr);
            const int gc = q + (wid < rr ? 1 : 0);
            const int beg = g0 * 16;
            int end = (g0 + gc) * 16;
            end = (end < n) ? end : n;
            for (int s = beg + l; s - l < end; s += 64) {
                const bool flg =
                    (s < end) && ((unsigned)out[s] & 0x80000000u);
                unsigned long long mk = __ballot(flg);
                while (mk) {
                    const int src = (int)__ffsll((unsigned long long)mk) - 1;
                    mk &= mk - 1;
                    const int pt = __shfl(s, src);
                    fix_point(X, s_mu, s_msq, out, pt, l);
                }
            }
        }
    }
}

// Fallback scan fixup over all of out (used only if ws too small).
__global__ void __launch_bounds__(256)
fixup_scan_lds_kernel(const float* __restrict__ X,
                      const float* __restrict__ mus,
                      int* __restrict__ out, int n) {
    __shared__ float s_mu[NPROTO * MSTRIDE];  // 65 KB
    __shared__ float s_msq[NPROTO];

    const int tid = threadIdx.x;
    {
        const float4* mr = (const float4*)(mus + (size_t)tid * DIM);
        float q0 = 0.f, q1 = 0.f, q2 = 0.f, q3 = 0.f;
#pragma unroll
        for (int qq = 0; qq < 16; ++qq) {
            const float4 mv = mr[qq];
            const int base = tid * MSTRIDE + qq * 4;
            s_mu[base]     = mv.x;
            s_mu[base + 1] = mv.y;
            s_mu[base + 2] = mv.z;
            s_mu[base + 3] = mv.w;
            q0 = fmaf(mv.x, mv.x, q0);
            q1 = fmaf(mv.y, mv.y, q1);
            q2 = fmaf(mv.z, mv.z, q2);
            q3 = fmaf(mv.w, mv.w, q3);
        }
        s_msq[tid] = (q0 + q1) + (q2 + q3);
    }
    __syncthreads();

    const int l = tid & 63;
    const int gw = (int)((blockIdx.x * blockDim.x + tid) >> 6);
    const int NW = (int)((gridDim.x * blockDim.x) >> 6);
    const int chunk = (n + NW - 1) / NW;
    const int base = gw * chunk;
    const int end = (base + chunk < n) ? (base + chunk) : n;

    for (int s = base; s < end; s += 64) {
        const int i = s + l;
        const int v = (i < end) ? out[i] : 0;
        const bool flg = (i < end) && ((unsigned)v & 0x80000000u);
        unsigned long long m = __ballot(flg);
        while (m) {
            const int src = (int)__ffsll((unsigned long long)m) - 1;
            m &= m - 1;
            const int pt = __shfl(i, src);
            fix_point(X, s_mu, s_msq, out, pt, l);
        }
    }
}

extern "C" void kernel_launch(void* const* d_in, const int* in_sizes, int n_in,
                              void* d_out, int out_size, void* d_ws, size_t ws_size,
                              hipStream_t stream) {
    const float* X = (const float*)d_in[0];
    const float* mus = (const float*)d_in[1];
    int* out = (int*)d_out;
    const int n = in_sizes[0] / DIM;  // 500000

    unsigned* ws_cnt = (unsigned*)d_ws;                       // [4096]
    int* ws_seg = (int*)((char*)d_ws + NWAVE * 4);            // [4096][SEGC]
    const size_t need = (size_t)NWAVE * 4 + (size_t)NWAVE * SEGC * 4;
    const int use_list = (ws_size >= need) ? 1 : 0;

    // TWO dispatches total: no memset (per-wave counts are fully
    // overwritten every call -> replay-safe even from 0xAA poison).
    argmin_mfma_kernel<<<NBLK, 256, 0, stream>>>(X, mus, out, ws_cnt,
                                                 ws_seg, use_list, n);
    if (use_list) {
        fixup_seg_kernel<<<512, 256, 0, stream>>>(X, mus, ws_cnt, ws_seg,
                                                  out, n);
    } else {
        fixup_scan_lds_kernel<<<512, 256, 0, stream>>>(X, mus, out, n);
    }
}

// Round 26
// 76.043 us; speedup vs baseline: 1.0527x; 1.0527x over previous
//
#include <hip/hip_runtime.h>

// Nearest-prototype argmin: N=500k, K=256, D=64, fp32.
// FINAL = R22 verbatim (best measured: 76.3us, absmax=0). Structure:
//  - main: 4 autonomous waves/block; all 256 protos as pre-arranged fp16
//    MFMA fragments in LDS (32KB, lane-linear, conflict-free); -musq/2
//    seed table read into the MFMA C operand; packed-index argmax (index
//    in low 8 mantissa bits -> pure fmax/fmin top-2); zero in-loop
//    barriers; full-iteration-distance X prefetch; natural VGPR
//    allocation (waves_per_eu attribute proved to force a 64-VGPR spill).
//  - margin 0.017 safety net: close top-2 gaps -> compacted list (ballot +
//    one atomic per wave) -> LDS-staged exact-fp32 fixup (R13-proven).
// Session trajectory: 509 -> 76.3us; 13 structural probes on the residual
// wall all null -> plateau of this structure at HIP level.

#define DIM 64
#define NPROTO 256
#define NBLK 1024
#define MARGIN_ACC 0.017f

using f32x4 = __attribute__((ext_vector_type(4))) float;
using f16x8 = __attribute__((ext_vector_type(8))) _Float16;

__device__ __forceinline__ f16x8 cvt8(float4 a, float4 b) {
    f16x8 r;
    r[0] = (_Float16)a.x; r[1] = (_Float16)a.y;
    r[2] = (_Float16)a.z; r[3] = (_Float16)a.w;
    r[4] = (_Float16)b.x; r[5] = (_Float16)b.y;
    r[6] = (_Float16)b.z; r[7] = (_Float16)b.w;
    return r;
}

__global__ void __launch_bounds__(256)
argmin_mfma_kernel(const float* __restrict__ X,
                   const float* __restrict__ mus,
                   int* __restrict__ out,
                   unsigned* __restrict__ ws_count,
                   int* __restrict__ ws_list,
                   int use_list, int n) {
    // [p][kt][lane]: lane l's fragment for proto-tile p, K-half kt.
    // Lane-linear 16B chunks -> ds_read_b128 is sequential, conflict-free.
    __shared__ __align__(16) f16x8 s_frag[16][2][64];   // 32 KB
    __shared__ __align__(16) float s_seed[NPROTO];      // -0.5*musq

    const int tid = threadIdx.x;   // 256 = 4 waves
    const int w = tid >> 6;
    const int l = tid & 63;
    const int lp = l & 15;         // A-row / B-col lane index
    const int lg = l >> 4;         // k-group

    // ---- prologue: wave w stages proto-tiles p = w*4 .. w*4+3.
    // Fragment values and musq op order identical to R17 (absmax=0). ----
#pragma unroll
    for (int pp = 0; pp < 4; ++pp) {
        const int p = w * 4 + pp;
        const float* src = mus + (size_t)(p * 16 + lp) * DIM + lg * 8;
        const float4 a = *(const float4*)(src);
        const float4 b = *(const float4*)(src + 4);
        const float4 c = *(const float4*)(src + 32);
        const float4 d = *(const float4*)(src + 36);
        s_frag[p][0][l] = cvt8(a, b);
        s_frag[p][1][l] = cvt8(c, d);
        float s = 0.f;
        s = fmaf(a.x, a.x, fmaf(a.y, a.y, fmaf(a.z, a.z, fmaf(a.w, a.w, s))));
        s = fmaf(b.x, b.x, fmaf(b.y, b.y, fmaf(b.z, b.z, fmaf(b.w, b.w, s))));
        s = fmaf(c.x, c.x, fmaf(c.y, c.y, fmaf(c.z, c.z, fmaf(c.w, c.w, s))));
        s = fmaf(d.x, d.x, fmaf(d.y, d.y, fmaf(d.z, d.z, fmaf(d.w, d.w, s))));
        s += __shfl_xor(s, 16);
        s += __shfl_xor(s, 32);
        if (lg == 0) s_seed[p * 16 + lp] = -0.5f * s;
    }
    __syncthreads();   // the ONLY barrier: publish fragments + seed

    // ---- 16-point group range per GLOBAL wave (autonomous) ----
    const int ngroups = (n + 15) / 16;   // 31250
    const int NW = NBLK * 4;
    const int gwid = blockIdx.x * 4 + w;
    const int q = ngroups / NW, rr = ngroups % NW;
    const int g0 = gwid * q + (gwid < rr ? gwid : rr);
    const int cnt = q + (gwid < rr ? 1 : 0);

    const int kofs = 255 - lg * 4;   // packed value = 255 - kk

    // prefetch group g0 (lane: row g*16+lp, dims lg*8 + kt*32)
    float4 xr0, xr1, xr2, xr3;
    if (cnt > 0) {
        int row = g0 * 16 + lp; row = (row < n) ? row : (n - 1);
        const float* rp = X + (size_t)row * DIM + lg * 8;
        xr0 = *(const float4*)(rp);
        xr1 = *(const float4*)(rp + 4);
        xr2 = *(const float4*)(rp + 32);
        xr3 = *(const float4*)(rp + 36);
    }

    for (int it = 0; it < cnt; ++it) {
        const int g = g0 + it;
        const bool more = (it + 1 < cnt);

        const f16x8 bx0 = cvt8(xr0, xr1);
        const f16x8 bx1 = cvt8(xr2, xr3);

        // issue next group's loads; consumed next iteration (no barriers
        // in the loop -> they stay in flight across the whole body)
        if (more) {
            int row = (g + 1) * 16 + lp; row = (row < n) ? row : (n - 1);
            const float* rp = X + (size_t)row * DIM + lg * 8;
            xr0 = *(const float4*)(rp);
            xr1 = *(const float4*)(rp + 4);
            xr2 = *(const float4*)(rp + 32);
            xr3 = *(const float4*)(rp + 36);
        }

        float b1 = -3.4e38f, b2 = -3.4e38f;
#pragma unroll
        for (int p = 0; p < 16; ++p) {
            // A-frags from LDS (constant offsets after unroll); values
            // identical to R17's register copies
            const f16x8 A0 = s_frag[p][0][l];
            const f16x8 A1 = s_frag[p][1][l];
            const f32x4 seed = *(const f32x4*)&s_seed[p * 16 + lg * 4];
            f32x4 acc = __builtin_amdgcn_mfma_f32_16x16x32_f16(
                A0, bx0, seed, 0, 0, 0);
            acc = __builtin_amdgcn_mfma_f32_16x16x32_f16(A1, bx1, acc,
                                                         0, 0, 0);
            // pack index into low 8 mantissa bits (bits cleared: no carry)
            float pv[4];
#pragma unroll
            for (int r = 0; r < 4; ++r) {
                unsigned u = __float_as_uint(acc[r]);
                u = (u & 0xFFFFFF00u) + (unsigned)(kofs - p * 16 - r);
                pv[r] = __uint_as_float(u);
            }
            const float t1a = fmaxf(pv[0], pv[1]), t2a = fminf(pv[0], pv[1]);
            const float t1b = fmaxf(pv[2], pv[3]), t2b = fminf(pv[2], pv[3]);
            const float p1 = fmaxf(t1a, t1b);
            const float p2 = fmaxf(fminf(t1a, t1b), fmaxf(t2a, t2b));
            const float nb2 = fmaxf(fminf(b1, p1), fmaxf(b2, p2));
            b1 = fmaxf(b1, p1);
            b2 = nb2;
        }
        // cross-lane over lg (4 lanes share point lp)
#pragma unroll
        for (int m = 16; m <= 32; m <<= 1) {
            const float o1 = __shfl_xor(b1, m);
            const float o2 = __shfl_xor(b2, m);
            const float nb2 = fmaxf(fminf(b1, o1), fmaxf(b2, o2));
            b1 = fmaxf(b1, o1);
            b2 = nb2;
        }

        bool fl = false;
        const int i = g * 16 + l;   // valid for l < 16
        if (l < 16 && i < n) {
            const unsigned u1 = __float_as_uint(b1);
            const int k1 = 255 - (int)(u1 & 0xFFu);
            const float v1 = __uint_as_float(u1 & 0xFFFFFF00u);
            const float v2 =
                __uint_as_float(__float_as_uint(b2) & 0xFFFFFF00u);
            const bool close = (v1 - v2) < MARGIN_ACC;
            if (use_list) {
                out[i] = k1;
                fl = close;
            } else {
                out[i] = (int)((unsigned)k1 | (close ? 0x80000000u : 0u));
            }
        }
        if (use_list) {
            const unsigned long long mask = __ballot(fl);
            if (mask) {
                unsigned base = 0;
                if (l == 0)
                    base = atomicAdd(ws_count, (unsigned)__popcll(mask));
                base = __shfl(base, 0);
                if (fl)
                    ws_list[base + __popcll(mask & ((1ull << l) - 1))] = i;
            }
        }
    }
}

#define MSTRIDE 65   // padded row stride: bank (l+d)%32, 2 lanes/bank = free

// LDS-staged exact-fp32 fixup over the compacted list (R13-proven).
__global__ void __launch_bounds__(256)
fixup_lds_kernel(const float* __restrict__ X, const float* __restrict__ mus,
                 const unsigned* __restrict__ ws_count,
                 const int* __restrict__ ws_list, int* __restrict__ out) {
    __shared__ float s_mu[NPROTO * MSTRIDE];  // 65 KB
    __shared__ float s_msq[NPROTO];

    const int tid = threadIdx.x;
    {
        const float4* mr = (const float4*)(mus + (size_t)tid * DIM);
        float q0 = 0.f, q1 = 0.f, q2 = 0.f, q3 = 0.f;
#pragma unroll
        for (int qq = 0; qq < 16; ++qq) {
            const float4 mv = mr[qq];
            const int base = tid * MSTRIDE + qq * 4;
            s_mu[base]     = mv.x;
            s_mu[base + 1] = mv.y;
            s_mu[base + 2] = mv.z;
            s_mu[base + 3] = mv.w;
            q0 = fmaf(mv.x, mv.x, q0);
            q1 = fmaf(mv.y, mv.y, q1);
            q2 = fmaf(mv.z, mv.z, q2);
            q3 = fmaf(mv.w, mv.w, q3);
        }
        s_msq[tid] = (q0 + q1) + (q2 + q3);
    }
    __syncthreads();

    const int l = tid & 63;
    const int gw = (int)((blockIdx.x * blockDim.x + tid) >> 6);
    const int NW = (int)((gridDim.x * blockDim.x) >> 6);
    const int nf = (int)*ws_count;

    for (int j = gw; j < nf; j += NW) {
        const int pt = ws_list[j];
        const float4* xr = (const float4*)(X + (size_t)pt * DIM);
        float4 xv[16];
        float a0 = 0.f, a1 = 0.f, a2 = 0.f, a3 = 0.f;
#pragma unroll
        for (int qq = 0; qq < 16; ++qq) {
            xv[qq] = xr[qq];
            a0 = fmaf(xv[qq].x, xv[qq].x, a0);
            a1 = fmaf(xv[qq].y, xv[qq].y, a1);
            a2 = fmaf(xv[qq].z, xv[qq].z, a2);
            a3 = fmaf(xv[qq].w, xv[qq].w, a3);
        }
        const float xsq = (a0 + a1) + (a2 + a3);
        float b1 = 3.4e38f;
        int k1 = 0;
#pragma unroll
        for (int e = 0; e < 4; ++e) {
            const int p = e * 64 + l;           // k ascending per lane
            const float* mr = &s_mu[p * MSTRIDE];
            float d0 = 0.f, d1 = 0.f, d2 = 0.f, d3 = 0.f;
#pragma unroll
            for (int qq = 0; qq < 16; ++qq) {
                d0 = fmaf(mr[qq * 4],     xv[qq].x, d0);
                d1 = fmaf(mr[qq * 4 + 1], xv[qq].y, d1);
                d2 = fmaf(mr[qq * 4 + 2], xv[qq].z, d2);
                d3 = fmaf(mr[qq * 4 + 3], xv[qq].w, d3);
            }
            const float dot = (d0 + d1) + (d2 + d3);
            const float dd = (xsq - 2.0f * dot) + s_msq[p];
            if (dd < b1) { b1 = dd; k1 = p; }   // strict <: first-min
        }
#pragma unroll
        for (int mm = 1; mm < 64; mm <<= 1) {
            const float ob = __shfl_xor(b1, mm);
            const int ok = __shfl_xor(k1, mm);
            if (ob < b1 || (ob == b1 && ok < k1)) { b1 = ob; k1 = ok; }
        }
        if (l == 0) out[pt] = k1;
    }
}

// Fallback scan fixup with LDS-staged mus (used only if ws too small).
__global__ void __launch_bounds__(256)
fixup_scan_lds_kernel(const float* __restrict__ X,
                      const float* __restrict__ mus,
                      int* __restrict__ out, int n) {
    __shared__ float s_mu[NPROTO * MSTRIDE];  // 65 KB
    __shared__ float s_msq[NPROTO];

    const int tid = threadIdx.x;
    {
        const float4* mr = (const float4*)(mus + (size_t)tid * DIM);
        float q0 = 0.f, q1 = 0.f, q2 = 0.f, q3 = 0.f;
#pragma unroll
        for (int qq = 0; qq < 16; ++qq) {
            const float4 mv = mr[qq];
            const int base = tid * MSTRIDE + qq * 4;
            s_mu[base]     = mv.x;
            s_mu[base + 1] = mv.y;
            s_mu[base + 2] = mv.z;
            s_mu[base + 3] = mv.w;
            q0 = fmaf(mv.x, mv.x, q0);
            q1 = fmaf(mv.y, mv.y, q1);
            q2 = fmaf(mv.z, mv.z, q2);
            q3 = fmaf(mv.w, mv.w, q3);
        }
        s_msq[tid] = (q0 + q1) + (q2 + q3);
    }
    __syncthreads();

    const int l = tid & 63;
    const int gw = (int)((blockIdx.x * blockDim.x + tid) >> 6);
    const int NW = (int)((gridDim.x * blockDim.x) >> 6);
    const int chunk = (n + NW - 1) / NW;
    const int base = gw * chunk;
    const int end = (base + chunk < n) ? (base + chunk) : n;

    for (int s = base; s < end; s += 64) {
        const int i = s + l;
        const int v = (i < end) ? out[i] : 0;
        const bool flg = (i < end) && ((unsigned)v & 0x80000000u);
        unsigned long long m = __ballot(flg);
        while (m) {
            const int src = (int)__ffsll((unsigned long long)m) - 1;
            m &= m - 1;
            const int pt = __shfl(i, src);
            const float4* xr = (const float4*)(X + (size_t)pt * DIM);
            float4 xv[16];
            float a0 = 0.f, a1 = 0.f, a2 = 0.f, a3 = 0.f;
#pragma unroll
            for (int qq = 0; qq < 16; ++qq) {
                xv[qq] = xr[qq];
                a0 = fmaf(xv[qq].x, xv[qq].x, a0);
                a1 = fmaf(xv[qq].y, xv[qq].y, a1);
                a2 = fmaf(xv[qq].z, xv[qq].z, a2);
                a3 = fmaf(xv[qq].w, xv[qq].w, a3);
            }
            const float xsq = (a0 + a1) + (a2 + a3);
            float b1 = 3.4e38f;
            int k1 = 0;
#pragma unroll
            for (int e = 0; e < 4; ++e) {
                const int p = e * 64 + l;
                const float* mr = &s_mu[p * MSTRIDE];
                float d0 = 0.f, d1 = 0.f, d2 = 0.f, d3 = 0.f;
#pragma unroll
                for (int qq = 0; qq < 16; ++qq) {
                    d0 = fmaf(mr[qq * 4],     xv[qq].x, d0);
                    d1 = fmaf(mr[qq * 4 + 1], xv[qq].y, d1);
                    d2 = fmaf(mr[qq * 4 + 2], xv[qq].z, d2);
                    d3 = fmaf(mr[qq * 4 + 3], xv[qq].w, d3);
                }
                const float dot = (d0 + d1) + (d2 + d3);
                const float dd = (xsq - 2.0f * dot) + s_msq[p];
                if (dd < b1) { b1 = dd; k1 = p; }
            }
#pragma unroll
            for (int mm = 1; mm < 64; mm <<= 1) {
                const float ob = __shfl_xor(b1, mm);
                const int ok = __shfl_xor(k1, mm);
                if (ob < b1 || (ob == b1 && ok < k1)) { b1 = ob; k1 = ok; }
            }
            if (l == 0) out[pt] = k1;
        }
    }
}

extern "C" void kernel_launch(void* const* d_in, const int* in_sizes, int n_in,
                              void* d_out, int out_size, void* d_ws, size_t ws_size,
                              hipStream_t stream) {
    const float* X = (const float*)d_in[0];
    const float* mus = (const float*)d_in[1];
    int* out = (int*)d_out;
    const int n = in_sizes[0] / DIM;  // 500000

    unsigned* ws_count = (unsigned*)d_ws;
    int* ws_list = (int*)((char*)d_ws + 16);
    const int use_list = (ws_size >= 16 + (size_t)n * 4) ? 1 : 0;

    if (use_list) {
        hipMemsetAsync(d_ws, 0, 16, stream);  // reset append counter
    }

    argmin_mfma_kernel<<<NBLK, 256, 0, stream>>>(X, mus, out, ws_count,
                                                 ws_list, use_list, n);
    if (use_list) {
        fixup_lds_kernel<<<512, 256, 0, stream>>>(X, mus, ws_count, ws_list,
                                                  out);
    } else {
        fixup_scan_lds_kernel<<<512, 256, 0, stream>>>(X, mus, out, n);
    }
}